// Round 1
// baseline (1679.577 us; speedup 1.0000x reference)
//
#include <hip/hip_runtime.h>

#define NEG_SLOPE 0.2f

// ---- float<->uint monotone encoding for atomic float max ----
__device__ __forceinline__ unsigned fenc(float f) {
    unsigned u = __float_as_uint(f);
    return (u & 0x80000000u) ? ~u : (u | 0x80000000u);
}
__device__ __forceinline__ float fdec(unsigned u) {
    return (u & 0x80000000u) ? __uint_as_float(u ^ 0x80000000u)
                             : __uint_as_float(~u);
}

// ---- Kernel 1: ft = h @ W  (one wave per row), fused el/er dots ----
// h: [n,64], W: [64,256], al/ar: [4,64], ft: [n,256], el/er: [n,4]
__global__ __launch_bounds__(256) void gat_gemm(
        const float* __restrict__ h, const float* __restrict__ Wl,
        const float* __restrict__ al, const float* __restrict__ ar,
        float* __restrict__ ft, float* __restrict__ el, float* __restrict__ er,
        int n) {
    int wid  = (int)((blockIdx.x * blockDim.x + threadIdx.x) >> 6);
    int lane = threadIdx.x & 63;
    if (wid >= n) return;

    float hreg = h[(size_t)wid * 64 + lane];   // lane holds h[row, lane]
    int c0 = lane * 4;                          // 4 output cols per lane
    float4 acc = make_float4(0.f, 0.f, 0.f, 0.f);
    #pragma unroll
    for (int k = 0; k < 64; ++k) {
        float hk = __shfl(hreg, k);
        float4 w4 = *(const float4*)(Wl + k * 256 + c0);
        acc.x += hk * w4.x; acc.y += hk * w4.y;
        acc.z += hk * w4.z; acc.w += hk * w4.w;
    }
    *(float4*)(ft + (size_t)wid * 256 + c0) = acc;

    // attention dots: head = lane>>4, 16 lanes per head cover 64 feats
    int hh = lane >> 4;
    int j4 = (lane & 15) * 4;
    float4 a4 = *(const float4*)(al + hh * 64 + j4);
    float4 b4 = *(const float4*)(ar + hh * 64 + j4);
    float pl = acc.x*a4.x + acc.y*a4.y + acc.z*a4.z + acc.w*a4.w;
    float pr = acc.x*b4.x + acc.y*b4.y + acc.z*b4.z + acc.w*b4.w;
    #pragma unroll
    for (int m = 1; m < 16; m <<= 1) {
        pl += __shfl_xor(pl, m);
        pr += __shfl_xor(pr, m);
    }
    if ((lane & 15) == 0) {
        el[(size_t)wid * 4 + hh] = pl;
        er[(size_t)wid * 4 + hh] = pr;
    }
}

// ---- Kernel 2 (pass A): e = leaky_relu(el[src]+er[dst]); segment max ----
__global__ __launch_bounds__(256) void gat_edge_a(
        const int* __restrict__ src, const int* __restrict__ dst,
        const float4* __restrict__ el4, const float4* __restrict__ er4,
        float4* __restrict__ ebuf, unsigned* __restrict__ emax, int ne) {
    int e = blockIdx.x * blockDim.x + threadIdx.x;
    if (e >= ne) return;
    int s = src[e], d = dst[e];
    float4 l4 = el4[s], r4 = er4[d];
    float4 ev;
    ev.x = l4.x + r4.x; ev.x = ev.x > 0.f ? ev.x : NEG_SLOPE * ev.x;
    ev.y = l4.y + r4.y; ev.y = ev.y > 0.f ? ev.y : NEG_SLOPE * ev.y;
    ev.z = l4.z + r4.z; ev.z = ev.z > 0.f ? ev.z : NEG_SLOPE * ev.z;
    ev.w = l4.w + r4.w; ev.w = ev.w > 0.f ? ev.w : NEG_SLOPE * ev.w;
    ebuf[e] = ev;
    unsigned* em = emax + (size_t)d * 4;
    atomicMax(em + 0, fenc(ev.x));
    atomicMax(em + 1, fenc(ev.y));
    atomicMax(em + 2, fenc(ev.z));
    atomicMax(em + 3, fenc(ev.w));
}

// ---- Kernel 3 (pass B): ee = exp(e - emax[dst]); segment sum -> denom ----
__global__ __launch_bounds__(256) void gat_edge_b(
        const int* __restrict__ dst, float4* __restrict__ ebuf,
        const uint4* __restrict__ emax4, float* __restrict__ denom, int ne) {
    int e = blockIdx.x * blockDim.x + threadIdx.x;
    if (e >= ne) return;
    int d = dst[e];
    float4 ev = ebuf[e];
    uint4 mu = emax4[d];
    float4 ee;
    ee.x = expf(ev.x - fdec(mu.x));
    ee.y = expf(ev.y - fdec(mu.y));
    ee.z = expf(ev.z - fdec(mu.z));
    ee.w = expf(ev.w - fdec(mu.w));
    ebuf[e] = ee;
    float* dn = denom + (size_t)d * 4;
    atomicAdd(dn + 0, ee.x);
    atomicAdd(dn + 1, ee.y);
    atomicAdd(dn + 2, ee.z);
    atomicAdd(dn + 3, ee.w);
}

// ---- Kernel 4 (pass C): out[dst,f] += sum_h ft[src,h,f] * alpha[e,h] ----
// one wave per edge, lane = feature
__global__ __launch_bounds__(256) void gat_edge_c(
        const int* __restrict__ src, const int* __restrict__ dst,
        const float4* __restrict__ ebuf, const float4* __restrict__ denom4,
        const float* __restrict__ ft, float* __restrict__ out, int ne) {
    int w    = (int)((blockIdx.x * blockDim.x + threadIdx.x) >> 6);
    int lane = threadIdx.x & 63;
    if (w >= ne) return;
    int s = src[w], d = dst[w];
    float4 ee = ebuf[w];
    float4 dn = denom4[d];
    float a0 = ee.x / dn.x, a1 = ee.y / dn.y, a2 = ee.z / dn.z, a3 = ee.w / dn.w;
    const float* fts = ft + (size_t)s * 256;
    float acc = fts[lane]       * a0
              + fts[64  + lane] * a1
              + fts[128 + lane] * a2
              + fts[192 + lane] * a3;
    atomicAdd(out + (size_t)d * 64 + lane, acc);
}

// ---- Kernel 5: out[n,f] += sum_h bias[h,f] ----
__global__ __launch_bounds__(256) void gat_bias(
        float* __restrict__ out, const float* __restrict__ b, int total) {
    int i = blockIdx.x * blockDim.x + threadIdx.x;
    if (i >= total) return;
    int f = i & 63;
    out[i] += b[f] + b[64 + f] + b[128 + f] + b[192 + f];
}

extern "C" void kernel_launch(void* const* d_in, const int* in_sizes, int n_in,
                              void* d_out, int out_size, void* d_ws, size_t ws_size,
                              hipStream_t stream) {
    const float* feat = (const float*)d_in[0];
    const float* W    = (const float*)d_in[1];
    const float* al   = (const float*)d_in[2];
    const float* ar   = (const float*)d_in[3];
    const float* bias = (const float*)d_in[4];
    const int*   src  = (const int*)d_in[5];
    const int*   dst  = (const int*)d_in[6];
    float* out = (float*)d_out;

    const int N = in_sizes[0] / 64;   // 50000
    const int E = in_sizes[5];        // 500000
    const int L = 4;

    // workspace carve (floats)
    float* ws = (float*)d_ws;
    float*    ft    = ws;                                   // N*256
    float*    hA    = ft + (size_t)N * 256;                 // N*64
    float*    hB    = hA + (size_t)N * 64;                  // N*64
    float*    el    = hB + (size_t)N * 64;                  // N*4
    float*    er    = el + (size_t)N * 4;                   // N*4
    unsigned* emax  = (unsigned*)(er + (size_t)N * 4);      // N*4
    float*    denom = (float*)(emax + (size_t)N * 4);       // N*4
    float*    ebuf  = denom + (size_t)N * 4;                // E*4

    const float* hin = feat;
    for (int l = 0; l < L; ++l) {
        float* hout = (l == L - 1) ? out : ((l & 1) ? hB : hA);
        const float* Wl = W    + (size_t)l * 64 * 256;
        const float* all_ = al + (size_t)l * 256;
        const float* arl  = ar + (size_t)l * 256;
        const float* bl   = bias + (size_t)l * 256;

        hipMemsetAsync(emax,  0, (size_t)N * 4 * sizeof(unsigned), stream);
        hipMemsetAsync(denom, 0, (size_t)N * 4 * sizeof(float), stream);
        hipMemsetAsync(hout,  0, (size_t)N * 64 * sizeof(float), stream);

        // GEMM + attention dots: one wave per row, 4 waves/block
        gat_gemm<<<(N + 3) / 4, 256, 0, stream>>>(hin, Wl, all_, arl, ft, el, er, N);
        // edge pass A
        gat_edge_a<<<(E + 255) / 256, 256, 0, stream>>>(
            src, dst, (const float4*)el, (const float4*)er,
            (float4*)ebuf, emax, E);
        // edge pass B
        gat_edge_b<<<(E + 255) / 256, 256, 0, stream>>>(
            dst, (float4*)ebuf, (const uint4*)emax, denom, E);
        // edge pass C: one wave per edge
        gat_edge_c<<<(E + 3) / 4, 256, 0, stream>>>(
            src, dst, (const float4*)ebuf, (const float4*)denom, ft, hout, E);
        // bias (sum over heads)
        gat_bias<<<((size_t)N * 64 + 255) / 256, 256, 0, stream>>>(hout, bl, N * 64);

        hin = hout;
    }
}

// Round 2
// 703.125 us; speedup vs baseline: 2.3887x; 2.3887x over previous
//
#include <hip/hip_runtime.h>

#define NEG_SLOPE 0.2f
#define FINF __builtin_inff()

// ================= prologue kernels (once per call) =================

__global__ __launch_bounds__(256) void k_deg(const int* __restrict__ dst,
                                             int* __restrict__ deg, int ne) {
    int e = blockIdx.x * blockDim.x + threadIdx.x;
    if (e < ne) atomicAdd(&deg[dst[e]], 1);
}

// single-block exclusive scan over deg[0..n) -> rowptr[0..n], cursor copy
__global__ __launch_bounds__(1024) void k_scan(const int* __restrict__ deg,
                                               int* __restrict__ rowptr,
                                               int* __restrict__ cursor, int n) {
    __shared__ int wsum[16];
    __shared__ int carry_s;
    int t = threadIdx.x, lane = t & 63, w = t >> 6;
    if (t == 0) carry_s = 0;
    __syncthreads();
    for (int base = 0; base < n; base += 1024) {
        int i = base + t;
        int v = (i < n) ? deg[i] : 0;
        int s = v;
        #pragma unroll
        for (int off = 1; off < 64; off <<= 1) {
            int y = __shfl_up(s, off);
            if (lane >= off) s += y;
        }
        if (lane == 63) wsum[w] = s;
        __syncthreads();
        if (w == 0 && lane < 16) {
            int ws = wsum[lane];
            #pragma unroll
            for (int off = 1; off < 16; off <<= 1) {
                int y = __shfl_up(ws, off);
                if (lane >= off) ws += y;
            }
            wsum[lane] = ws;   // inclusive scan of wave sums
        }
        __syncthreads();
        int carry = carry_s;
        int wexcl = (w > 0) ? wsum[w - 1] : 0;
        int excl = carry + wexcl + s - v;
        if (i < n) { rowptr[i] = excl; cursor[i] = excl; }
        __syncthreads();
        if (t == 0) carry_s = carry + wsum[15];
        __syncthreads();
    }
    if (t == 0) rowptr[n] = carry_s;
}

__global__ __launch_bounds__(256) void k_scatter(const int* __restrict__ src,
                                                 const int* __restrict__ dst,
                                                 int* __restrict__ cursor,
                                                 int* __restrict__ csr_src, int ne) {
    int e = blockIdx.x * blockDim.x + threadIdx.x;
    if (e >= ne) return;
    int pos = atomicAdd(&cursor[dst[e]], 1);
    csr_src[pos] = src[e];
}

// W[l][k][h*64+f] -> Wt[l][k][f*4+h]   (all 4 layers)
__global__ __launch_bounds__(256) void k_transW(const float* __restrict__ W,
                                                float* __restrict__ Wt) {
    int i = blockIdx.x * blockDim.x + threadIdx.x;
    if (i >= 4 * 64 * 256) return;
    int l = i >> 14, r = i & 16383;
    int k = r >> 8, c = r & 255;
    int f = c >> 2, h = c & 3;
    Wt[i] = W[(l << 14) + (k << 8) + h * 64 + f];
}

// al/ar[l][h][f] -> alT/arT[l][f*4+h]; bsum[l][f] = sum_h bias[l][h][f]
__global__ __launch_bounds__(256) void k_transA(const float* __restrict__ al,
                                                const float* __restrict__ ar,
                                                const float* __restrict__ bias,
                                                float* __restrict__ alT,
                                                float* __restrict__ arT,
                                                float* __restrict__ bsum) {
    int i = blockIdx.x * blockDim.x + threadIdx.x;
    if (i < 4 * 256) {
        int l = i >> 8, c = i & 255;
        int f = c >> 2, h = c & 3;
        alT[i] = al[(l << 8) + h * 64 + f];
        arT[i] = ar[(l << 8) + h * 64 + f];
    }
    if (i < 4 * 64) {
        int l = i >> 6, f = i & 63;
        float s = 0.f;
        #pragma unroll
        for (int h = 0; h < 4; ++h) s += bias[(l << 8) + h * 64 + f];
        bsum[i] = s;
    }
}

// ================= per-layer kernels =================

// ft = h @ W (8 rows per wave, register-blocked), fused el/er dots.
// ft layout: [row][f][h] (h innermost, float4 per lane at f=lane)
__global__ __launch_bounds__(256) void k_gemm(
        const float* __restrict__ h, const float* __restrict__ Wt,
        const float* __restrict__ alT, const float* __restrict__ arT,
        float* __restrict__ ft, float* __restrict__ el, float* __restrict__ er,
        int n) {
    int wid  = (int)((blockIdx.x * blockDim.x + threadIdx.x) >> 6);
    int lane = threadIdx.x & 63;
    int r0 = wid * 8;
    if (r0 >= n) return;

    float hreg[8];
    #pragma unroll
    for (int j = 0; j < 8; ++j)
        hreg[j] = (r0 + j < n) ? h[(size_t)(r0 + j) * 64 + lane] : 0.f;

    float4 acc[8];
    #pragma unroll
    for (int j = 0; j < 8; ++j) acc[j] = make_float4(0.f, 0.f, 0.f, 0.f);

    #pragma unroll 8
    for (int k = 0; k < 64; ++k) {
        float4 w4 = *(const float4*)(Wt + (k << 8) + (lane << 2));
        #pragma unroll
        for (int j = 0; j < 8; ++j) {
            float hk = __shfl(hreg[j], k);
            acc[j].x += hk * w4.x; acc[j].y += hk * w4.y;
            acc[j].z += hk * w4.z; acc[j].w += hk * w4.w;
        }
    }

    float4 a4 = *(const float4*)(alT + (lane << 2));
    float4 b4 = *(const float4*)(arT + (lane << 2));

    #pragma unroll
    for (int j = 0; j < 8; ++j) {
        int r = r0 + j;
        if (r >= n) break;
        *(float4*)(ft + (size_t)r * 256 + (lane << 2)) = acc[j];
        float4 pl, pr;
        pl.x = acc[j].x * a4.x; pl.y = acc[j].y * a4.y;
        pl.z = acc[j].z * a4.z; pl.w = acc[j].w * a4.w;
        pr.x = acc[j].x * b4.x; pr.y = acc[j].y * b4.y;
        pr.z = acc[j].z * b4.z; pr.w = acc[j].w * b4.w;
        #pragma unroll
        for (int m = 1; m < 64; m <<= 1) {
            pl.x += __shfl_xor(pl.x, m); pl.y += __shfl_xor(pl.y, m);
            pl.z += __shfl_xor(pl.z, m); pl.w += __shfl_xor(pl.w, m);
            pr.x += __shfl_xor(pr.x, m); pr.y += __shfl_xor(pr.y, m);
            pr.z += __shfl_xor(pr.z, m); pr.w += __shfl_xor(pr.w, m);
        }
        if (lane == 0) {
            *(float4*)(el + (size_t)r * 4) = pl;
            *(float4*)(er + (size_t)r * 4) = pr;
        }
    }
}

// Fused edge-softmax + aggregation + bias. One wave per dst node.
// lane = (ei<<2)|h for softmax phases; lane = feature f for aggregation.
__global__ __launch_bounds__(256) void k_agg(
        const int* __restrict__ rowptr, const int* __restrict__ csr_src,
        const float* __restrict__ el, const float* __restrict__ er,
        const float* __restrict__ ft, const float* __restrict__ bsum,
        float* __restrict__ out, int n) {
    __shared__ float lds_ee[4][64];
    __shared__ int   lds_s[4][16];
    int wid  = (int)((blockIdx.x * blockDim.x + threadIdx.x) >> 6);
    int w    = (threadIdx.x >> 6) & 3;
    int lane = threadIdx.x & 63;
    if (wid >= n) return;
    int d = wid;
    int rbeg = rowptr[d], rend = rowptr[d + 1];
    float bs = bsum[lane];
    if (rend == rbeg) { out[(size_t)d * 64 + lane] = bs; return; }

    int ei = lane >> 2, hh = lane & 3;
    float erh = er[(size_t)d * 4 + hh];

    // pass 1: per-head max over incoming edges
    float m = -FINF;
    for (int base = rbeg; base < rend; base += 16) {
        int idx = base + ei;
        float ev = -FINF;
        if (idx < rend) {
            int s = csr_src[idx];
            float x = el[(size_t)s * 4 + hh] + erh;
            ev = x > 0.f ? x : NEG_SLOPE * x;
        }
        m = fmaxf(m, ev);
    }
    #pragma unroll
    for (int msk = 4; msk < 64; msk <<= 1) m = fmaxf(m, __shfl_xor(m, msk));

    // pass 2: ee = exp(e - m); accumulate denom and unnormalized per-head sums
    float dsum = 0.f;
    float4 acc = make_float4(0.f, 0.f, 0.f, 0.f);
    for (int base = rbeg; base < rend; base += 16) {
        int idx = base + ei;
        int e16 = min(16, rend - base);
        float ee = 0.f;
        if (idx < rend) {
            int s = csr_src[idx];
            float x = el[(size_t)s * 4 + hh] + erh;
            x = x > 0.f ? x : NEG_SLOPE * x;
            ee = __expf(x - m);
            dsum += ee;
            if (hh == 0) lds_s[w][ei] = s;
        }
        lds_ee[w][lane] = ee;
        for (int i = 0; i < e16; ++i) {
            float4 ee4 = *(float4*)&lds_ee[w][i * 4];
            int s = lds_s[w][i];
            float4 f4 = *(const float4*)(ft + (size_t)s * 256 + (lane << 2));
            acc.x += ee4.x * f4.x; acc.y += ee4.y * f4.y;
            acc.z += ee4.z * f4.z; acc.w += ee4.w * f4.w;
        }
    }
    #pragma unroll
    for (int msk = 4; msk < 64; msk <<= 1) dsum += __shfl_xor(dsum, msk);
    float d0 = __shfl(dsum, 0), d1 = __shfl(dsum, 1);
    float d2 = __shfl(dsum, 2), d3 = __shfl(dsum, 3);
    out[(size_t)d * 64 + lane] = acc.x / d0 + acc.y / d1 + acc.z / d2 + acc.w / d3 + bs;
}

// ================= launcher =================

extern "C" void kernel_launch(void* const* d_in, const int* in_sizes, int n_in,
                              void* d_out, int out_size, void* d_ws, size_t ws_size,
                              hipStream_t stream) {
    const float* feat = (const float*)d_in[0];
    const float* W    = (const float*)d_in[1];
    const float* al   = (const float*)d_in[2];
    const float* ar   = (const float*)d_in[3];
    const float* bias = (const float*)d_in[4];
    const int*   src  = (const int*)d_in[5];
    const int*   dst  = (const int*)d_in[6];
    float* out = (float*)d_out;

    const int N = in_sizes[0] / 64;   // 50000
    const int E = in_sizes[5];        // 500000
    const int L = 4;

    // workspace carve
    float* ws = (float*)d_ws;
    float* ft   = ws;                                  // N*256
    float* hA   = ft + (size_t)N * 256;                // N*64
    float* hB   = hA + (size_t)N * 64;                 // N*64
    float* el   = hB + (size_t)N * 64;                 // N*4
    float* er   = el + (size_t)N * 4;                  // N*4
    float* Wt   = er + (size_t)N * 4;                  // 4*16384
    float* alT  = Wt + 4 * 16384;                      // 4*256
    float* arT  = alT + 4 * 256;                       // 4*256
    float* bsum = arT + 4 * 256;                       // 4*64
    int* rowptr  = (int*)(bsum + 4 * 64);              // N+1
    int* cursor  = rowptr + (N + 1);                   // N
    int* deg     = cursor + N;                         // N
    int* csr_src = deg + N;                            // E

    // ---- prologue: CSR build + weight transposes (once per call) ----
    hipMemsetAsync(deg, 0, (size_t)N * sizeof(int), stream);
    k_deg<<<(E + 255) / 256, 256, 0, stream>>>(dst, deg, E);
    k_scan<<<1, 1024, 0, stream>>>(deg, rowptr, cursor, N);
    k_scatter<<<(E + 255) / 256, 256, 0, stream>>>(src, dst, cursor, csr_src, E);
    k_transW<<<(4 * 64 * 256 + 255) / 256, 256, 0, stream>>>(W, Wt);
    k_transA<<<4, 256, 0, stream>>>(al, ar, bias, alT, arT, bsum);

    // ---- layers ----
    const float* hin = feat;
    for (int l = 0; l < L; ++l) {
        float* hout = (l == L - 1) ? out : ((l & 1) ? hB : hA);
        int nwaves = (N + 7) / 8;
        k_gemm<<<(nwaves * 64 + 255) / 256, 256, 0, stream>>>(
            hin, Wt + (size_t)l * 16384, alT + (size_t)l * 256,
            arT + (size_t)l * 256, ft, el, er, N);
        k_agg<<<((size_t)N * 64 + 255) / 256, 256, 0, stream>>>(
            rowptr, csr_src, el, er, ft, bsum + (size_t)l * 64, hout, N);
        hin = hout;
    }
}